// Round 4
// baseline (378.645 us; speedup 1.0000x reference)
//
#include <hip/hip_runtime.h>
#include <hip/hip_bf16.h>
#include <string.h>

#define BB 128
#define UU 200
#define DD 512
#define NP 256

typedef __attribute__((ext_vector_type(8))) short short8;
typedef __attribute__((ext_vector_type(4))) float f32x4;
typedef __attribute__((ext_vector_type(16))) float f32x16;

__device__ __forceinline__ unsigned pack_bf16_2(float a, float b) {
    __hip_bfloat162 h = __float22bfloat162_rn(make_float2(a, b));
    unsigned u; memcpy(&u, &h, 4); return u;
}

__device__ __forceinline__ unsigned short f2bf(float x) {
    union { float f; unsigned u; } v; v.f = x;
    unsigned r = v.u + 0x7FFFu + ((v.u >> 16) & 1u);
    return (unsigned short)(r >> 16);
}

// async global->LDS, 16B per lane; LDS dest = wave-uniform base + lane*16
__device__ __forceinline__ void glds16(const float* g, float* l) {
    __builtin_amdgcn_global_load_lds(
        (const __attribute__((address_space(1))) unsigned*)g,
        (__attribute__((address_space(3))) unsigned*)l, 16, 0, 0);
}

// ---- build plain bf16 tables Kbr[n][j], Kbi[n][j] (n padded to 256 with zeros).
// Also pre-zeroes out[] (25600 < 131072, same stream => done before gemm atomics).
__global__ void kb2_build_kernel(const float* __restrict__ Kt,
                                 unsigned short* __restrict__ Kbr,
                                 unsigned short* __restrict__ Kbi,
                                 float* __restrict__ out) {
    int idx = blockIdx.x * 256 + threadIdx.x;    // 0..131071 (256 n x 512 j)
    int n = idx >> 9, j = idx & 511;
    unsigned short r = 0, im = 0;
    if (n < UU) {
        float2 s = ((const float2*)Kt)[(size_t)n * DD + j];
        r = f2bf(s.x); im = f2bf(s.y);
    }
    Kbr[idx] = r;
    Kbi[idx] = im;
    if (idx < BB * UU) out[idx] = 0.0f;
}

__global__ void zero_out_kernel(float* __restrict__ out) {
    int i = blockIdx.x * 256 + threadIdx.x;
    if (i < BB * UU) out[i] = 0.0f;
}

// ---- quadratic-form GEMM, v4 (32x32 MFMA + global_load_lds):
//   Mr[i,n] = sum_j Ar[b,i,j]*kr[n,j] - Ai[b,i,j]*ki[n,j]
//   Mi[i,n] = sum_j Ar[b,i,j]*ki[n,j] + Ai[b,i,j]*kr[n,j]
//   out[b,n] += sum_i kr[n,i]*Mr[i,n] - ki[n,i]*Mi[i,n]   (i-contraction in-block)
// Block = (b, 32-row i-chunk): grid 2048, 512 thr = 8 waves. Wave w owns n-tile
// [32w,32w+32) as ONE 32x32x16 MFMA tile (acc = 32 regs). Wave 7's n-tile
// (224..255) is all zero padding -> skipped. A staged fp32 via global_load_lds
// (swizzled SOURCE address, linear LDS dest), converted bf16 at read. Kb loads
// are the only VMEM-to-reg ops, issued first each substage so their vmcnt waits
// never drain the in-flight A stream. 32 KB LDS dbuf; 2 blocks/CU.
__global__ __launch_bounds__(512, 5) void qf_gemm_kernel(
    const float* __restrict__ Ar, const float* __restrict__ Ai,
    const float* __restrict__ Kt,
    const unsigned short* __restrict__ Kbr, const unsigned short* __restrict__ Kbi,
    float* __restrict__ out)
{
    __shared__ float sAf[2][2][32 * 64];   // [dbuf][Ar/Ai][row*64 + col'*4], 32 KB

    const int tid  = threadIdx.x;
    const int bx   = blockIdx.x;           // 0..2047
    const int b    = bx >> 4;
    const int i0   = (bx & 15) * 32;

    const int w    = tid >> 6;             // 0..7
    const int lane = tid & 63;
    const int l31  = lane & 31;            // MFMA row (A) / col (B,C)
    const int h    = lane >> 5;            // k-half selector
    const int key  = l31 & 15;             // read-side swizzle key

    // staging: wave w stages rows [4w,4w+4) of Ar and Ai (4 rows x 16 granules)
    // lane l -> row 4w + (l>>4), LDS col' = l&15, global col = col' ^ (row&15)
    const int srow = w * 4 + (lane >> 4);
    const int scol = (lane & 15) ^ (srow & 15);
    const float* gR = Ar + ((size_t)b * DD + i0 + srow) * DD + scol * 4;
    const float* gI = Ai + ((size_t)b * DD + i0 + srow) * DD + scol * 4;
    const int ldsbase = w * 4 * 64;        // wave-uniform float offset

    // Kb row pointers (wave w: n rows 32w + l31)
    const unsigned short* kbrp = Kbr + (size_t)(w * 32 + l31) * 512 + h * 8;
    const unsigned short* kbip = Kbi + (size_t)(w * 32 + l31) * 512 + h * 8;

    // fragment read offsets (floats): frag ks covers j = ks*16 + h*8 + 0..7
    const int rb = l31 * 64;
    int off0[4];
#pragma unroll
    for (int ks = 0; ks < 4; ++ks) {
        int c0 = ks * 4 + 2 * h;           // even -> off1 = off0 ^ 4
        off0[ks] = rb + ((c0 ^ key) << 2);
    }

    f32x16 accr, acci;
#pragma unroll
    for (int e = 0; e < 16; ++e) { accr[e] = 0.f; acci[e] = 0.f; }

    // prologue: stage substage 0 into buf 0
    glds16(gR, &sAf[0][0][ldsbase]);
    glds16(gI, &sAf[0][1][ldsbase]);

#pragma unroll 2
    for (int ss = 0; ss < 8; ++ss) {
        __syncthreads();                   // vmcnt(0) drain = dbuf handshake
        const float* bufR = &sAf[ss & 1][0][0];
        const float* bufI = &sAf[ss & 1][1][0];

        // Kb fragments FIRST (only reg-VMEM: waits touch nothing else)
        short8 kr[4], ki[4];
        if (w < 7) {
            const unsigned short* krp = kbrp + ss * 64;
            const unsigned short* kip = kbip + ss * 64;
#pragma unroll
            for (int ks = 0; ks < 4; ++ks) {
                kr[ks] = *(const short8*)(krp + ks * 16);
                ki[ks] = *(const short8*)(kip + ks * 16);
            }
        }
        __builtin_amdgcn_sched_barrier(0); // keep glds issue AFTER kb issue

        // async-stage next substage (arrives before next barrier's drain)
        if (ss < 7) {
            glds16(gR + (ss + 1) * 64, &sAf[(ss + 1) & 1][0][ldsbase]);
            glds16(gI + (ss + 1) * 64, &sAf[(ss + 1) & 1][1][ldsbase]);
        }

        if (w < 7) {
#pragma unroll
            for (int ks = 0; ks < 4; ++ks) {
                const int o0 = off0[ks], o1 = off0[ks] ^ 4;
                f32x4 a0 = *(const f32x4*)&bufR[o0];
                f32x4 a1 = *(const f32x4*)&bufR[o1];
                f32x4 b0 = *(const f32x4*)&bufI[o0];
                f32x4 b1 = *(const f32x4*)&bufI[o1];
                union { short8 v; unsigned u[4]; } fr, fi, nk;
                fr.u[0] = pack_bf16_2(a0[0], a0[1]);
                fr.u[1] = pack_bf16_2(a0[2], a0[3]);
                fr.u[2] = pack_bf16_2(a1[0], a1[1]);
                fr.u[3] = pack_bf16_2(a1[2], a1[3]);
                fi.u[0] = pack_bf16_2(b0[0], b0[1]);
                fi.u[1] = pack_bf16_2(b0[2], b0[3]);
                fi.u[2] = pack_bf16_2(b1[0], b1[1]);
                fi.u[3] = pack_bf16_2(b1[2], b1[3]);
                nk.v = ki[ks];
#pragma unroll
                for (int e = 0; e < 4; ++e) nk.u[e] ^= 0x80008000u;
                accr = __builtin_amdgcn_mfma_f32_32x32x16_bf16(fr.v, kr[ks], accr, 0, 0, 0);
                acci = __builtin_amdgcn_mfma_f32_32x32x16_bf16(fr.v, ki[ks], acci, 0, 0, 0);
                accr = __builtin_amdgcn_mfma_f32_32x32x16_bf16(fi.v, nk.v, accr, 0, 0, 0);
                acci = __builtin_amdgcn_mfma_f32_32x32x16_bf16(fi.v, kr[ks], acci, 0, 0, 0);
            }
        }
    }

    // ---- epilogue: i-contraction with f32 kernel, cross-half reduce, one atomic
    // C/D 32x32 layout: col = l31, row = (reg&3) + 8*(reg>>2) + 4*h
    if (w < 7) {
        const int n = w * 32 + l31;
        float s = 0.f;
        if (n < UU) {
            const float* kp = Kt + ((size_t)n * DD + i0 + 4 * h) * 2;  // (kr,ki)
#pragma unroll
            for (int q = 0; q < 4; ++q) {
                f32x4 k01 = *(const f32x4*)(kp + q * 16);      // rows 8q+4h+0,1
                f32x4 k23 = *(const f32x4*)(kp + q * 16 + 4);  // rows 8q+4h+2,3
                s += accr[q * 4 + 0] * k01[0] - acci[q * 4 + 0] * k01[1];
                s += accr[q * 4 + 1] * k01[2] - acci[q * 4 + 1] * k01[3];
                s += accr[q * 4 + 2] * k23[0] - acci[q * 4 + 2] * k23[1];
                s += accr[q * 4 + 3] * k23[2] - acci[q * 4 + 3] * k23[3];
            }
        }
        s += __shfl_xor(s, 32, 64);        // combine h=0/h=1 row-halves (same n)
        if (h == 0 && n < UU)
            atomicAdd(&out[(size_t)b * UU + n], s);  // 16 i-chunks per (b,n)
    }
}

// ---- fallback (ws too small): self-contained atomic kernel, f32 Kt synthesis in LDS
#define ASTR 40
#define WSTR 40
__global__ __launch_bounds__(512, 4) void cm_gemm_fb_kernel(
    const float* __restrict__ Ar, const float* __restrict__ Ai,
    const float* __restrict__ Kt, float* __restrict__ dst)
{
    __shared__ short sAr[BB * ASTR];
    __shared__ short sAi[BB * ASTR];
    __shared__ short sWr[NP * WSTR];
    __shared__ short sWi[NP * WSTR];
    const int tid = threadIdx.x, irow = blockIdx.x;
    const int w = tid >> 6, lane = tid & 63;
    const int mw = (w & 1) * 64, nw = (w >> 1) * 64;
    const int rrow = lane & 15, quad = lane >> 4;
    const int nW = tid >> 1, jh = (tid & 1) * 16;
    float krI = 0.f, kiI = 0.f;
    if (nW < UU) { float2 s = ((const float2*)Kt)[(size_t)nW * DD + irow]; krI = s.x; kiI = s.y; }
    const int brow0 = tid >> 3, grp = tid & 7;
    const size_t aoff0 = (size_t)brow0 * DD * DD + (size_t)irow * DD + (size_t)grp * 4;
    const size_t aoff1 = aoff0 + (size_t)64 * DD * DD;
    f32x4 acc[4][4];
#pragma unroll
    for (int a = 0; a < 4; ++a)
#pragma unroll
        for (int c = 0; c < 4; ++c) acc[a][c] = (f32x4)(0.f);
    for (int jw = 0; jw < DD; jw += 32) {
        f32x4 vr0 = *(const f32x4*)(Ar + aoff0 + jw);
        f32x4 vr1 = *(const f32x4*)(Ar + aoff1 + jw);
        f32x4 vi0 = *(const f32x4*)(Ai + aoff0 + jw);
        f32x4 vi1 = *(const f32x4*)(Ai + aoff1 + jw);
        union { unsigned short s[4]; uint2 u; } t0, t1, t2, t3;
#pragma unroll
        for (int q = 0; q < 4; ++q) {
            t0.s[q] = f2bf(vr0[q]); t1.s[q] = f2bf(vr1[q]);
            t2.s[q] = f2bf(vi0[q]); t3.s[q] = f2bf(vi1[q]);
        }
        *(uint2*)&sAr[ brow0       * ASTR + grp * 4] = t0.u;
        *(uint2*)&sAr[(brow0 + 64) * ASTR + grp * 4] = t1.u;
        *(uint2*)&sAi[ brow0       * ASTR + grp * 4] = t2.u;
        *(uint2*)&sAi[(brow0 + 64) * ASTR + grp * 4] = t3.u;
        if (nW < UU) {
            const f32x4* kv = (const f32x4*)(Kt + (size_t)nW * DD * 2 + (size_t)(jw + jh) * 2);
#pragma unroll
            for (int q = 0; q < 8; ++q) {
                f32x4 v = kv[q];
                float wr0 = krI * v[0] - kiI * v[1], wi0 = -(krI * v[1] + kiI * v[0]);
                float wr1 = krI * v[2] - kiI * v[3], wi1 = -(krI * v[3] + kiI * v[2]);
                *(unsigned*)&sWr[nW * WSTR + jh + 2 * q] = (unsigned)f2bf(wr0) | ((unsigned)f2bf(wr1) << 16);
                *(unsigned*)&sWi[nW * WSTR + jh + 2 * q] = (unsigned)f2bf(wi0) | ((unsigned)f2bf(wi1) << 16);
            }
        } else {
#pragma unroll
            for (int q = 0; q < 8; ++q) {
                *(unsigned*)&sWr[nW * WSTR + jh + 2 * q] = 0u;
                *(unsigned*)&sWi[nW * WSTR + jh + 2 * q] = 0u;
            }
        }
        __syncthreads();
#pragma unroll
        for (int ph = 0; ph < 2; ++ph) {
            const short* sA = ph ? sAi : sAr;
            const short* sW = ph ? sWi : sWr;
            short8 af[4], bf[4];
#pragma unroll
            for (int t = 0; t < 4; ++t) {
                af[t] = *(const short8*)&sA[(mw + t * 16 + rrow) * ASTR + quad * 8];
                bf[t] = *(const short8*)&sW[(nw + t * 16 + rrow) * WSTR + quad * 8];
            }
#pragma unroll
            for (int ti = 0; ti < 4; ++ti)
#pragma unroll
                for (int tj = 0; tj < 4; ++tj)
                    acc[ti][tj] = __builtin_amdgcn_mfma_f32_16x16x32_bf16(af[ti], bf[tj], acc[ti][tj], 0, 0, 0);
        }
        __syncthreads();
    }
#pragma unroll
    for (int ti = 0; ti < 4; ++ti) {
        int m = mw + ti * 16 + quad * 4;
#pragma unroll
        for (int tj = 0; tj < 4; ++tj) {
            int n = nw + tj * 16 + rrow;
            if (n < UU)
#pragma unroll
                for (int r = 0; r < 4; ++r)
                    atomicAdd(&dst[(size_t)(m + r) * UU + n], acc[ti][tj][r]);
        }
    }
}

extern "C" void kernel_launch(void* const* d_in, const int* in_sizes, int n_in,
                              void* d_out, int out_size, void* d_ws, size_t ws_size,
                              hipStream_t stream) {
    const float* Ar = (const float*)d_in[0];
    const float* Ai = (const float*)d_in[1];
    const float* Kt = (const float*)d_in[2];
    float* out = (float*)d_out;

    const size_t kb_need = (size_t)2 * NP * DD * sizeof(unsigned short);  // 512 KB

    if (ws_size >= kb_need) {
        unsigned short* Kbr = (unsigned short*)d_ws;
        unsigned short* Kbi = Kbr + (size_t)NP * DD;
        hipLaunchKernelGGL(kb2_build_kernel, dim3(512), dim3(256), 0, stream, Kt, Kbr, Kbi, out);
        hipLaunchKernelGGL(qf_gemm_kernel, dim3(2048), dim3(512), 0, stream,
                           Ar, Ai, Kt, Kbr, Kbi, out);
    } else {
        hipLaunchKernelGGL(zero_out_kernel, dim3(100), dim3(256), 0, stream, out);
        hipLaunchKernelGGL(cm_gemm_fb_kernel, dim3(DD), dim3(512), 0, stream, Ar, Ai, Kt, out);
    }
}

// Round 5
// 349.945 us; speedup vs baseline: 1.0820x; 1.0820x over previous
//
#include <hip/hip_runtime.h>
#include <hip/hip_bf16.h>
#include <string.h>

#define BB 128
#define UU 200
#define DD 512
#define NP 256

typedef __attribute__((ext_vector_type(8))) short short8;
typedef __attribute__((ext_vector_type(4))) float f32x4;
typedef __attribute__((ext_vector_type(16))) float f32x16;

__device__ __forceinline__ unsigned pack_bf16_2(float a, float b) {
    __hip_bfloat162 h = __float22bfloat162_rn(make_float2(a, b));
    unsigned u; memcpy(&u, &h, 4); return u;
}

__device__ __forceinline__ unsigned short f2bf(float x) {
    union { float f; unsigned u; } v; v.f = x;
    unsigned r = v.u + 0x7FFFu + ((v.u >> 16) & 1u);
    return (unsigned short)(r >> 16);
}

// raw barrier WITHOUT vmcnt drain: LDS handshake only. Keeps A/kb loads in
// flight across the barrier (the m97 ~20% stall fix, T3/T4 pattern).
#define QF_BAR()                                              \
    do {                                                      \
        __builtin_amdgcn_sched_barrier(0);                    \
        asm volatile("s_waitcnt lgkmcnt(0)" ::: "memory");    \
        __builtin_amdgcn_s_barrier();                         \
        __builtin_amdgcn_sched_barrier(0);                    \
    } while (0)

// ---- build plain bf16 tables Kbr[n][j], Kbi[n][j] (n padded to 256 with zeros).
// Also pre-zeroes out[] (25600 < 131072, same stream => done before gemm atomics).
__global__ void kb2_build_kernel(const float* __restrict__ Kt,
                                 unsigned short* __restrict__ Kbr,
                                 unsigned short* __restrict__ Kbi,
                                 float* __restrict__ out) {
    int idx = blockIdx.x * 256 + threadIdx.x;    // 0..131071 (256 n x 512 j)
    int n = idx >> 9, j = idx & 511;
    unsigned short r = 0, im = 0;
    if (n < UU) {
        float2 s = ((const float2*)Kt)[(size_t)n * DD + j];
        r = f2bf(s.x); im = f2bf(s.y);
    }
    Kbr[idx] = r;
    Kbi[idx] = im;
    if (idx < BB * UU) out[idx] = 0.0f;
}

__global__ void zero_out_kernel(float* __restrict__ out) {
    int i = blockIdx.x * 256 + threadIdx.x;
    if (i < BB * UU) out[i] = 0.0f;
}

// ---- quadratic-form GEMM, v5 (32x32 MFMA, bf16 LDS, raw-barrier pipeline):
//   Mr[i,n] = sum_j Ar[b,i,j]*kr[n,j] - Ai[b,i,j]*ki[n,j]
//   Mi[i,n] = sum_j Ar[b,i,j]*ki[n,j] + Ai[b,i,j]*kr[n,j]
//   out[b,n] += sum_i kr[n,i]*Mr[i,n] - ki[n,i]*Mi[i,n]   (i-contraction in-block)
// Block = (b, 32-row i-chunk): grid 2048, 512 thr = 8 waves; wave w owns n-tile
// [32w,32w+32) (one 32x32 MFMA tile, acc = 32 AGPR); wave 7 = zero padding,
// skipped. A: global fp32 -> regs (issued late ss-1) -> cvt+ds_write bf16 late
// ss (T14 split, ~1 substage flight). kb: 2 half-sets (ks01/ks23) refilled for
// ss+1 right after last use in ss (L2 latency hidden). Barriers are raw
// s_barrier + lgkmcnt(0) ONLY - no vmcnt(0) drain, loads fly across.
// launch_bounds(512,4): 128-reg cap (round-4 spilled at the (512,5)=102 cap),
// ~102 regs used -> 2 blocks/CU co-resident.
__global__ __launch_bounds__(512, 4) void qf_gemm_kernel(
    const float* __restrict__ Ar, const float* __restrict__ Ai,
    const float* __restrict__ Kt,
    const unsigned short* __restrict__ Kbr, const unsigned short* __restrict__ Kbi,
    float* __restrict__ out)
{
    __shared__ __align__(16) short sB[2][2][32 * 64];  // [dbuf][R/I][row*64+swz], 16 KB

    const int tid  = threadIdx.x;
    const int bx   = blockIdx.x;           // 0..2047
    const int b    = bx >> 4;
    const int i0   = (bx & 15) * 32;

    const int w    = tid >> 6;             // 0..7
    const int lane = tid & 63;
    const int l31  = lane & 31;            // MFMA row (A) / col (B,C)
    const int h    = lane >> 5;            // k-half selector

    // staging: thread -> (row r0, 4-float granule g); coalesced 256B per 16 lanes
    const int r0 = tid >> 4;               // 0..31
    const int g  = tid & 15;
    const float* gR = Ar + ((size_t)b * DD + i0 + r0) * DD + g * 4;
    const float* gI = Ai + ((size_t)b * DD + i0 + r0) * DD + g * 4;
    // bf16 write addr (shorts): row*64 + swizzled 16B-slot + half-slot
    const int wa = r0 * 64 + ((((g >> 1) ^ (r0 & 7))) << 3) + (g & 1) * 4;

    // bf16 read offsets (shorts): row l31, 16B slot (2ks+h) ^ (l31&7) -> even
    // bank spread (8 words/bank/wave), conflict-free
    int roff[4];
#pragma unroll
    for (int ks = 0; ks < 4; ++ks)
        roff[ks] = l31 * 64 + ((((ks << 1) + h) ^ (l31 & 7)) << 3);

    const unsigned short* kbrp = Kbr + (size_t)(w * 32 + l31) * 512 + h * 8;
    const unsigned short* kbip = Kbi + (size_t)(w * 32 + l31) * 512 + h * 8;

    f32x16 accr, acci;
#pragma unroll
    for (int e = 0; e < 16; ++e) { accr[e] = 0.f; acci[e] = 0.f; }

    short8 kAr[2], kAi[2], kBr[2], kBi[2];   // kb half-sets (ks01 / ks23)
    f32x4 pfR, pfI;                          // fp32 A staging regs

    // ---- prologue: kb[0] both halves, A[0] -> buf0, A[1] in flight
    if (w < 7) {
        kAr[0] = *(const short8*)(kbrp +  0);
        kAi[0] = *(const short8*)(kbip +  0);
        kAr[1] = *(const short8*)(kbrp + 16);
        kAi[1] = *(const short8*)(kbip + 16);
        kBr[0] = *(const short8*)(kbrp + 32);
        kBi[0] = *(const short8*)(kbip + 32);
        kBr[1] = *(const short8*)(kbrp + 48);
        kBi[1] = *(const short8*)(kbip + 48);
    }
    pfR = *(const f32x4*)gR;
    pfI = *(const f32x4*)gI;
    {
        uint2 u;
        u.x = pack_bf16_2(pfR[0], pfR[1]); u.y = pack_bf16_2(pfR[2], pfR[3]);
        *(uint2*)&sB[0][0][wa] = u;
        u.x = pack_bf16_2(pfI[0], pfI[1]); u.y = pack_bf16_2(pfI[2], pfI[3]);
        *(uint2*)&sB[0][1][wa] = u;
    }
    pfR = *(const f32x4*)(gR + 64);
    pfI = *(const f32x4*)(gI + 64);
    QF_BAR();

#pragma unroll
    for (int ss = 0; ss < 8; ++ss) {
        const short* bufR = &sB[ss & 1][0][0];
        const short* bufI = &sB[ss & 1][1][0];

        // ---- MFMA ks0,ks1 (kA), then refill kA <- kb[ss+1].ks01
        if (w < 7) {
#pragma unroll
            for (int ks = 0; ks < 2; ++ks) {
                short8 ar = *(const short8*)&bufR[roff[ks]];
                short8 ai = *(const short8*)&bufI[roff[ks]];
                union { short8 v; unsigned u[4]; } nk;
                nk.v = kAi[ks];
#pragma unroll
                for (int e = 0; e < 4; ++e) nk.u[e] ^= 0x80008000u;
                accr = __builtin_amdgcn_mfma_f32_32x32x16_bf16(ar, kAr[ks], accr, 0, 0, 0);
                acci = __builtin_amdgcn_mfma_f32_32x32x16_bf16(ar, kAi[ks], acci, 0, 0, 0);
                accr = __builtin_amdgcn_mfma_f32_32x32x16_bf16(ai, nk.v,    accr, 0, 0, 0);
                acci = __builtin_amdgcn_mfma_f32_32x32x16_bf16(ai, kAr[ks], acci, 0, 0, 0);
            }
            if (ss < 7) {
                const unsigned short* krp = kbrp + (ss + 1) * 64;
                const unsigned short* kip = kbip + (ss + 1) * 64;
                kAr[0] = *(const short8*)(krp +  0);
                kAi[0] = *(const short8*)(kip +  0);
                kAr[1] = *(const short8*)(krp + 16);
                kAi[1] = *(const short8*)(kip + 16);
            }
        }

        // ---- MFMA ks2,ks3 (kB), then refill kB <- kb[ss+1].ks23
        if (w < 7) {
#pragma unroll
            for (int ks = 0; ks < 2; ++ks) {
                short8 ar = *(const short8*)&bufR[roff[2 + ks]];
                short8 ai = *(const short8*)&bufI[roff[2 + ks]];
                union { short8 v; unsigned u[4]; } nk;
                nk.v = kBi[ks];
#pragma unroll
                for (int e = 0; e < 4; ++e) nk.u[e] ^= 0x80008000u;
                accr = __builtin_amdgcn_mfma_f32_32x32x16_bf16(ar, kBr[ks], accr, 0, 0, 0);
                acci = __builtin_amdgcn_mfma_f32_32x32x16_bf16(ar, kBi[ks], acci, 0, 0, 0);
                accr = __builtin_amdgcn_mfma_f32_32x32x16_bf16(ai, nk.v,    accr, 0, 0, 0);
                acci = __builtin_amdgcn_mfma_f32_32x32x16_bf16(ai, kBr[ks], acci, 0, 0, 0);
            }
            if (ss < 7) {
                const unsigned short* krp = kbrp + (ss + 1) * 64;
                const unsigned short* kip = kbip + (ss + 1) * 64;
                kBr[0] = *(const short8*)(krp + 32);
                kBi[0] = *(const short8*)(kip + 32);
                kBr[1] = *(const short8*)(krp + 48);
                kBi[1] = *(const short8*)(kip + 48);
            }
        }

        // ---- stage-write A[ss+1] (cvt fp32->bf16), issue A[ss+2], barrier
        if (ss < 7) {
            uint2 u;
            u.x = pack_bf16_2(pfR[0], pfR[1]); u.y = pack_bf16_2(pfR[2], pfR[3]);
            *(uint2*)&sB[(ss + 1) & 1][0][wa] = u;
            u.x = pack_bf16_2(pfI[0], pfI[1]); u.y = pack_bf16_2(pfI[2], pfI[3]);
            *(uint2*)&sB[(ss + 1) & 1][1][wa] = u;
            if (ss < 6) {
                pfR = *(const f32x4*)(gR + (ss + 2) * 64);
                pfI = *(const f32x4*)(gI + (ss + 2) * 64);
            }
            QF_BAR();
        }
    }

    // ---- epilogue: i-contraction with f32 kernel, cross-half reduce, one atomic
    // C/D 32x32 layout: col = l31, row = (reg&3) + 8*(reg>>2) + 4*h  (verified)
    if (w < 7) {
        const int n = w * 32 + l31;
        float s = 0.f;
        if (n < UU) {
            const float* kp = Kt + ((size_t)n * DD + i0 + 4 * h) * 2;  // (kr,ki)
#pragma unroll
            for (int q = 0; q < 4; ++q) {
                f32x4 k01 = *(const f32x4*)(kp + q * 16);      // rows 8q+4h+0,1
                f32x4 k23 = *(const f32x4*)(kp + q * 16 + 4);  // rows 8q+4h+2,3
                s += accr[q * 4 + 0] * k01[0] - acci[q * 4 + 0] * k01[1];
                s += accr[q * 4 + 1] * k01[2] - acci[q * 4 + 1] * k01[3];
                s += accr[q * 4 + 2] * k23[0] - acci[q * 4 + 2] * k23[1];
                s += accr[q * 4 + 3] * k23[2] - acci[q * 4 + 3] * k23[3];
            }
        }
        s += __shfl_xor(s, 32, 64);        // combine h=0/h=1 row-halves (same n)
        if (h == 0 && n < UU)
            atomicAdd(&out[(size_t)b * UU + n], s);  // 16 i-chunks per (b,n)
    }
}

// ---- fallback (ws too small): self-contained atomic kernel, f32 Kt synthesis in LDS
#define ASTR 40
#define WSTR 40
__global__ __launch_bounds__(512, 4) void cm_gemm_fb_kernel(
    const float* __restrict__ Ar, const float* __restrict__ Ai,
    const float* __restrict__ Kt, float* __restrict__ dst)
{
    __shared__ short sAr[BB * ASTR];
    __shared__ short sAi[BB * ASTR];
    __shared__ short sWr[NP * WSTR];
    __shared__ short sWi[NP * WSTR];
    const int tid = threadIdx.x, irow = blockIdx.x;
    const int w = tid >> 6, lane = tid & 63;
    const int mw = (w & 1) * 64, nw = (w >> 1) * 64;
    const int rrow = lane & 15, quad = lane >> 4;
    const int nW = tid >> 1, jh = (tid & 1) * 16;
    float krI = 0.f, kiI = 0.f;
    if (nW < UU) { float2 s = ((const float2*)Kt)[(size_t)nW * DD + irow]; krI = s.x; kiI = s.y; }
    const int brow0 = tid >> 3, grp = tid & 7;
    const size_t aoff0 = (size_t)brow0 * DD * DD + (size_t)irow * DD + (size_t)grp * 4;
    const size_t aoff1 = aoff0 + (size_t)64 * DD * DD;
    f32x4 acc[4][4];
#pragma unroll
    for (int a = 0; a < 4; ++a)
#pragma unroll
        for (int c = 0; c < 4; ++c) acc[a][c] = (f32x4)(0.f);
    for (int jw = 0; jw < DD; jw += 32) {
        f32x4 vr0 = *(const f32x4*)(Ar + aoff0 + jw);
        f32x4 vr1 = *(const f32x4*)(Ar + aoff1 + jw);
        f32x4 vi0 = *(const f32x4*)(Ai + aoff0 + jw);
        f32x4 vi1 = *(const f32x4*)(Ai + aoff1 + jw);
        union { unsigned short s[4]; uint2 u; } t0, t1, t2, t3;
#pragma unroll
        for (int q = 0; q < 4; ++q) {
            t0.s[q] = f2bf(vr0[q]); t1.s[q] = f2bf(vr1[q]);
            t2.s[q] = f2bf(vi0[q]); t3.s[q] = f2bf(vi1[q]);
        }
        *(uint2*)&sAr[ brow0       * ASTR + grp * 4] = t0.u;
        *(uint2*)&sAr[(brow0 + 64) * ASTR + grp * 4] = t1.u;
        *(uint2*)&sAi[ brow0       * ASTR + grp * 4] = t2.u;
        *(uint2*)&sAi[(brow0 + 64) * ASTR + grp * 4] = t3.u;
        if (nW < UU) {
            const f32x4* kv = (const f32x4*)(Kt + (size_t)nW * DD * 2 + (size_t)(jw + jh) * 2);
#pragma unroll
            for (int q = 0; q < 8; ++q) {
                f32x4 v = kv[q];
                float wr0 = krI * v[0] - kiI * v[1], wi0 = -(krI * v[1] + kiI * v[0]);
                float wr1 = krI * v[2] - kiI * v[3], wi1 = -(krI * v[3] + kiI * v[2]);
                *(unsigned*)&sWr[nW * WSTR + jh + 2 * q] = (unsigned)f2bf(wr0) | ((unsigned)f2bf(wr1) << 16);
                *(unsigned*)&sWi[nW * WSTR + jh + 2 * q] = (unsigned)f2bf(wi0) | ((unsigned)f2bf(wi1) << 16);
            }
        } else {
#pragma unroll
            for (int q = 0; q < 8; ++q) {
                *(unsigned*)&sWr[nW * WSTR + jh + 2 * q] = 0u;
                *(unsigned*)&sWi[nW * WSTR + jh + 2 * q] = 0u;
            }
        }
        __syncthreads();
#pragma unroll
        for (int ph = 0; ph < 2; ++ph) {
            const short* sA = ph ? sAi : sAr;
            const short* sW = ph ? sWi : sWr;
            short8 af[4], bf[4];
#pragma unroll
            for (int t = 0; t < 4; ++t) {
                af[t] = *(const short8*)&sA[(mw + t * 16 + rrow) * ASTR + quad * 8];
                bf[t] = *(const short8*)&sW[(nw + t * 16 + rrow) * WSTR + quad * 8];
            }
#pragma unroll
            for (int ti = 0; ti < 4; ++ti)
#pragma unroll
                for (int tj = 0; tj < 4; ++tj)
                    acc[ti][tj] = __builtin_amdgcn_mfma_f32_16x16x32_bf16(af[ti], bf[tj], acc[ti][tj], 0, 0, 0);
        }
        __syncthreads();
    }
#pragma unroll
    for (int ti = 0; ti < 4; ++ti) {
        int m = mw + ti * 16 + quad * 4;
#pragma unroll
        for (int tj = 0; tj < 4; ++tj) {
            int n = nw + tj * 16 + rrow;
            if (n < UU)
#pragma unroll
                for (int r = 0; r < 4; ++r)
                    atomicAdd(&dst[(size_t)(m + r) * UU + n], acc[ti][tj][r]);
        }
    }
}

extern "C" void kernel_launch(void* const* d_in, const int* in_sizes, int n_in,
                              void* d_out, int out_size, void* d_ws, size_t ws_size,
                              hipStream_t stream) {
    const float* Ar = (const float*)d_in[0];
    const float* Ai = (const float*)d_in[1];
    const float* Kt = (const float*)d_in[2];
    float* out = (float*)d_out;

    const size_t kb_need = (size_t)2 * NP * DD * sizeof(unsigned short);  // 512 KB

    if (ws_size >= kb_need) {
        unsigned short* Kbr = (unsigned short*)d_ws;
        unsigned short* Kbi = Kbr + (size_t)NP * DD;
        hipLaunchKernelGGL(kb2_build_kernel, dim3(512), dim3(256), 0, stream, Kt, Kbr, Kbi, out);
        hipLaunchKernelGGL(qf_gemm_kernel, dim3(2048), dim3(512), 0, stream,
                           Ar, Ai, Kt, Kbr, Kbi, out);
    } else {
        hipLaunchKernelGGL(zero_out_kernel, dim3(100), dim3(256), 0, stream, out);
        hipLaunchKernelGGL(cm_gemm_fb_kernel, dim3(DD), dim3(512), 0, stream, Ar, Ai, Kt, out);
    }
}

// Round 7
// 305.882 us; speedup vs baseline: 1.2379x; 1.1441x over previous
//
#include <hip/hip_runtime.h>
#include <hip/hip_bf16.h>
#include <string.h>

#define BB 128
#define UU 200
#define DD 512
#define NP 256

typedef __attribute__((ext_vector_type(8))) short short8;
typedef __attribute__((ext_vector_type(4))) float f32x4;
typedef __attribute__((ext_vector_type(16))) float f32x16;

__device__ __forceinline__ unsigned pack_bf16_2(float a, float b) {
    __hip_bfloat162 h = __float22bfloat162_rn(make_float2(a, b));
    unsigned u; memcpy(&u, &h, 4); return u;
}

__device__ __forceinline__ unsigned short f2bf(float x) {
    union { float f; unsigned u; } v; v.f = x;
    unsigned r = v.u + 0x7FFFu + ((v.u >> 16) & 1u);
    return (unsigned short)(r >> 16);
}

// raw barrier WITHOUT vmcnt drain: LDS handshake only. Keeps A/kb loads in
// flight across the barrier (the m97 ~20% stall fix, T3/T4 pattern).
#define QF_BAR()                                              \
    do {                                                      \
        __builtin_amdgcn_sched_barrier(0);                    \
        asm volatile("s_waitcnt lgkmcnt(0)" ::: "memory");    \
        __builtin_amdgcn_s_barrier();                         \
        __builtin_amdgcn_sched_barrier(0);                    \
    } while (0)

// ---- build kb table in MFMA-B-FRAGMENT ORDER (coalesced per-wave loads):
// KbF[w][ss][chunk][lane][e]: chunk c -> table t=c&1 (0=kr,1=ki), ks=c>>1;
// lane l -> n = 32w + (l&31), j = ss*64 + ks*16 + (l>>5)*8 + e.
// Strides (shorts): lane=8, chunk=512, ss=4096, w=32768.
// A wave's fragment load = base + lane*16B : one contiguous 1KB dwordx4 load
// (v5's per-n-row layout scattered 32 x 64B lines per load -> L2 saturation).
// Also pre-zeroes out[] (25600 < 32768, same stream => before gemm atomics).
__global__ void kbf_build_kernel(const float* __restrict__ Kt,
                                 unsigned short* __restrict__ KbF,
                                 float* __restrict__ out) {
    int idx = blockIdx.x * 256 + threadIdx.x;    // 0..32767 (w8 x ss8 x c8 x lane64)
    int lane = idx & 63;
    int c    = (idx >> 6) & 7;
    int ss   = (idx >> 9) & 7;
    int w    = idx >> 12;
    int n  = w * 32 + (lane & 31);
    int t  = c & 1;
    int jb = ss * 64 + (c >> 1) * 16 + (lane >> 5) * 8;
    union { unsigned short s[8]; uint4 u; } o;
#pragma unroll
    for (int e = 0; e < 8; ++e) {
        float f = 0.f;
        if (n < UU) f = Kt[((size_t)n * DD + jb + e) * 2 + t];
        o.s[e] = f2bf(f);
    }
    *(uint4*)(KbF + (size_t)idx * 8) = o.u;
    if (idx < BB * UU) out[idx] = 0.0f;
}

__global__ void zero_out_kernel(float* __restrict__ out) {
    int i = blockIdx.x * 256 + threadIdx.x;
    if (i < BB * UU) out[i] = 0.0f;
}

// ---- quadratic-form GEMM, v6b (= v5 + fragment-order kb table; w-stride fixed):
//   Mr[i,n] = sum_j Ar[b,i,j]*kr[n,j] - Ai[b,i,j]*ki[n,j]
//   Mi[i,n] = sum_j Ar[b,i,j]*ki[n,j] + Ai[b,i,j]*kr[n,j]
//   out[b,n] += sum_i kr[n,i]*Mr[i,n] - ki[n,i]*Mi[i,n]   (i-contraction in-block)
// Block = (b, 32-row i-chunk): grid 2048, 512 thr = 8 waves; wave w owns n-tile
// [32w,32w+32) (one 32x32 MFMA tile, acc = 32 AGPR); wave 7 = zero padding,
// skipped. A: fp32 -> regs (issued late ss) -> cvt+ds_write bf16 late ss+1.
// kb: fragment-order table, 2 half-sets (ks01/ks23) refilled for ss+1 right
// after last use in ss -- each refill is a coalesced 1KB dwordx4 load.
// Barriers: raw s_barrier + lgkmcnt(0) only (no vmcnt drain).
__global__ __launch_bounds__(512, 4) void qf_gemm_kernel(
    const float* __restrict__ Ar, const float* __restrict__ Ai,
    const float* __restrict__ Kt,
    const unsigned short* __restrict__ KbF,
    float* __restrict__ out)
{
    __shared__ __align__(16) short sB[2][2][32 * 64];  // [dbuf][R/I][row*64+swz], 16 KB

    const int tid  = threadIdx.x;
    const int bx   = blockIdx.x;           // 0..2047
    const int b    = bx >> 4;
    const int i0   = (bx & 15) * 32;

    const int w    = tid >> 6;             // 0..7
    const int lane = tid & 63;
    const int l31  = lane & 31;            // MFMA row (A) / col (B,C)
    const int h    = lane >> 5;            // k-half selector

    // staging: thread -> (row r0, 4-float granule g); coalesced 256B per 16 lanes
    const int r0 = tid >> 4;               // 0..31
    const int g  = tid & 15;
    const float* gR = Ar + ((size_t)b * DD + i0 + r0) * DD + g * 4;
    const float* gI = Ai + ((size_t)b * DD + i0 + r0) * DD + g * 4;
    // bf16 write addr (shorts): row*64 + swizzled 16B-slot + half-slot
    const int wa = r0 * 64 + ((((g >> 1) ^ (r0 & 7))) << 3) + (g & 1) * 4;

    // bf16 read offsets (shorts): row l31, 16B slot (2ks+h) ^ (l31&7)
    int roff[4];
#pragma unroll
    for (int ks = 0; ks < 4; ++ks)
        roff[ks] = l31 * 64 + ((((ks << 1) + h) ^ (l31 & 7)) << 3);

    // fragment-order kb base: w stride 32768 shorts, ss stride 4096, chunk 512
    const unsigned short* kfb = KbF + ((size_t)w * 32768 + (size_t)lane * 8);

    f32x16 accr, acci;
#pragma unroll
    for (int e = 0; e < 16; ++e) { accr[e] = 0.f; acci[e] = 0.f; }

    short8 kAr[2], kAi[2], kBr[2], kBi[2];   // kb half-sets (ks01 / ks23)
    f32x4 pfR, pfI;                          // fp32 A staging regs

    // ---- prologue: kb[0] both halves, A[0] -> buf0, A[1] in flight
    if (w < 7) {
        kAr[0] = *(const short8*)(kfb +    0);
        kAi[0] = *(const short8*)(kfb +  512);
        kAr[1] = *(const short8*)(kfb + 1024);
        kAi[1] = *(const short8*)(kfb + 1536);
        kBr[0] = *(const short8*)(kfb + 2048);
        kBi[0] = *(const short8*)(kfb + 2560);
        kBr[1] = *(const short8*)(kfb + 3072);
        kBi[1] = *(const short8*)(kfb + 3584);
    }
    pfR = *(const f32x4*)gR;
    pfI = *(const f32x4*)gI;
    {
        uint2 u;
        u.x = pack_bf16_2(pfR[0], pfR[1]); u.y = pack_bf16_2(pfR[2], pfR[3]);
        *(uint2*)&sB[0][0][wa] = u;
        u.x = pack_bf16_2(pfI[0], pfI[1]); u.y = pack_bf16_2(pfI[2], pfI[3]);
        *(uint2*)&sB[0][1][wa] = u;
    }
    pfR = *(const f32x4*)(gR + 64);
    pfI = *(const f32x4*)(gI + 64);
    QF_BAR();

#pragma unroll
    for (int ss = 0; ss < 8; ++ss) {
        const short* bufR = &sB[ss & 1][0][0];
        const short* bufI = &sB[ss & 1][1][0];

        // ---- MFMA ks0,ks1 (kA), then refill kA <- kb[ss+1].ks01 (coalesced)
        if (w < 7) {
#pragma unroll
            for (int ks = 0; ks < 2; ++ks) {
                short8 ar = *(const short8*)&bufR[roff[ks]];
                short8 ai = *(const short8*)&bufI[roff[ks]];
                union { short8 v; unsigned u[4]; } nk;
                nk.v = kAi[ks];
#pragma unroll
                for (int e = 0; e < 4; ++e) nk.u[e] ^= 0x80008000u;
                accr = __builtin_amdgcn_mfma_f32_32x32x16_bf16(ar, kAr[ks], accr, 0, 0, 0);
                acci = __builtin_amdgcn_mfma_f32_32x32x16_bf16(ar, kAi[ks], acci, 0, 0, 0);
                accr = __builtin_amdgcn_mfma_f32_32x32x16_bf16(ai, nk.v,    accr, 0, 0, 0);
                acci = __builtin_amdgcn_mfma_f32_32x32x16_bf16(ai, kAr[ks], acci, 0, 0, 0);
            }
            if (ss < 7) {
                const unsigned short* kp = kfb + (size_t)(ss + 1) * 4096;
                kAr[0] = *(const short8*)(kp +    0);
                kAi[0] = *(const short8*)(kp +  512);
                kAr[1] = *(const short8*)(kp + 1024);
                kAi[1] = *(const short8*)(kp + 1536);
            }
        }

        // ---- MFMA ks2,ks3 (kB), then refill kB <- kb[ss+1].ks23 (coalesced)
        if (w < 7) {
#pragma unroll
            for (int ks = 0; ks < 2; ++ks) {
                short8 ar = *(const short8*)&bufR[roff[2 + ks]];
                short8 ai = *(const short8*)&bufI[roff[2 + ks]];
                union { short8 v; unsigned u[4]; } nk;
                nk.v = kBi[ks];
#pragma unroll
                for (int e = 0; e < 4; ++e) nk.u[e] ^= 0x80008000u;
                accr = __builtin_amdgcn_mfma_f32_32x32x16_bf16(ar, kBr[ks], accr, 0, 0, 0);
                acci = __builtin_amdgcn_mfma_f32_32x32x16_bf16(ar, kBi[ks], acci, 0, 0, 0);
                accr = __builtin_amdgcn_mfma_f32_32x32x16_bf16(ai, nk.v,    accr, 0, 0, 0);
                acci = __builtin_amdgcn_mfma_f32_32x32x16_bf16(ai, kBr[ks], acci, 0, 0, 0);
            }
            if (ss < 7) {
                const unsigned short* kp = kfb + (size_t)(ss + 1) * 4096;
                kBr[0] = *(const short8*)(kp + 2048);
                kBi[0] = *(const short8*)(kp + 2560);
                kBr[1] = *(const short8*)(kp + 3072);
                kBi[1] = *(const short8*)(kp + 3584);
            }
        }

        // ---- stage-write A[ss+1] (cvt fp32->bf16), issue A[ss+2], barrier
        if (ss < 7) {
            uint2 u;
            u.x = pack_bf16_2(pfR[0], pfR[1]); u.y = pack_bf16_2(pfR[2], pfR[3]);
            *(uint2*)&sB[(ss + 1) & 1][0][wa] = u;
            u.x = pack_bf16_2(pfI[0], pfI[1]); u.y = pack_bf16_2(pfI[2], pfI[3]);
            *(uint2*)&sB[(ss + 1) & 1][1][wa] = u;
            if (ss < 6) {
                pfR = *(const f32x4*)(gR + (ss + 2) * 64);
                pfI = *(const f32x4*)(gI + (ss + 2) * 64);
            }
            QF_BAR();
        }
    }

    // ---- epilogue: i-contraction with f32 kernel, cross-half reduce, one atomic
    // C/D 32x32 layout: col = l31, row = (reg&3) + 8*(reg>>2) + 4*h  (verified)
    if (w < 7) {
        const int n = w * 32 + l31;
        float s = 0.f;
        if (n < UU) {
            const float* kp = Kt + ((size_t)n * DD + i0 + 4 * h) * 2;  // (kr,ki)
#pragma unroll
            for (int q = 0; q < 4; ++q) {
                f32x4 k01 = *(const f32x4*)(kp + q * 16);      // rows 8q+4h+0,1
                f32x4 k23 = *(const f32x4*)(kp + q * 16 + 4);  // rows 8q+4h+2,3
                s += accr[q * 4 + 0] * k01[0] - acci[q * 4 + 0] * k01[1];
                s += accr[q * 4 + 1] * k01[2] - acci[q * 4 + 1] * k01[3];
                s += accr[q * 4 + 2] * k23[0] - acci[q * 4 + 2] * k23[1];
                s += accr[q * 4 + 3] * k23[2] - acci[q * 4 + 3] * k23[3];
            }
        }
        s += __shfl_xor(s, 32, 64);        // combine h=0/h=1 row-halves (same n)
        if (h == 0 && n < UU)
            atomicAdd(&out[(size_t)b * UU + n], s);  // 16 i-chunks per (b,n)
    }
}

// ---- fallback (ws too small): self-contained atomic kernel, f32 Kt synthesis in LDS
#define ASTR 40
#define WSTR 40
__global__ __launch_bounds__(512, 4) void cm_gemm_fb_kernel(
    const float* __restrict__ Ar, const float* __restrict__ Ai,
    const float* __restrict__ Kt, float* __restrict__ dst)
{
    __shared__ short sAr[BB * ASTR];
    __shared__ short sAi[BB * ASTR];
    __shared__ short sWr[NP * WSTR];
    __shared__ short sWi[NP * WSTR];
    const int tid = threadIdx.x, irow = blockIdx.x;
    const int w = tid >> 6, lane = tid & 63;
    const int mw = (w & 1) * 64, nw = (w >> 1) * 64;
    const int rrow = lane & 15, quad = lane >> 4;
    const int nW = tid >> 1, jh = (tid & 1) * 16;
    float krI = 0.f, kiI = 0.f;
    if (nW < UU) { float2 s = ((const float2*)Kt)[(size_t)nW * DD + irow]; krI = s.x; kiI = s.y; }
    const int brow0 = tid >> 3, grp = tid & 7;
    const size_t aoff0 = (size_t)brow0 * DD * DD + (size_t)irow * DD + (size_t)grp * 4;
    const size_t aoff1 = aoff0 + (size_t)64 * DD * DD;
    f32x4 acc[4][4];
#pragma unroll
    for (int a = 0; a < 4; ++a)
#pragma unroll
        for (int c = 0; c < 4; ++c) acc[a][c] = (f32x4)(0.f);
    for (int jw = 0; jw < DD; jw += 32) {
        f32x4 vr0 = *(const f32x4*)(Ar + aoff0 + jw);
        f32x4 vr1 = *(const f32x4*)(Ar + aoff1 + jw);
        f32x4 vi0 = *(const f32x4*)(Ai + aoff0 + jw);
        f32x4 vi1 = *(const f32x4*)(Ai + aoff1 + jw);
        union { unsigned short s[4]; uint2 u; } t0, t1, t2, t3;
#pragma unroll
        for (int q = 0; q < 4; ++q) {
            t0.s[q] = f2bf(vr0[q]); t1.s[q] = f2bf(vr1[q]);
            t2.s[q] = f2bf(vi0[q]); t3.s[q] = f2bf(vi1[q]);
        }
        *(uint2*)&sAr[ brow0       * ASTR + grp * 4] = t0.u;
        *(uint2*)&sAr[(brow0 + 64) * ASTR + grp * 4] = t1.u;
        *(uint2*)&sAi[ brow0       * ASTR + grp * 4] = t2.u;
        *(uint2*)&sAi[(brow0 + 64) * ASTR + grp * 4] = t3.u;
        if (nW < UU) {
            const f32x4* kv = (const f32x4*)(Kt + (size_t)nW * DD * 2 + (size_t)(jw + jh) * 2);
#pragma unroll
            for (int q = 0; q < 8; ++q) {
                f32x4 v = kv[q];
                float wr0 = krI * v[0] - kiI * v[1], wi0 = -(krI * v[1] + kiI * v[0]);
                float wr1 = krI * v[2] - kiI * v[3], wi1 = -(krI * v[3] + kiI * v[2]);
                *(unsigned*)&sWr[nW * WSTR + jh + 2 * q] = (unsigned)f2bf(wr0) | ((unsigned)f2bf(wr1) << 16);
                *(unsigned*)&sWi[nW * WSTR + jh + 2 * q] = (unsigned)f2bf(wi0) | ((unsigned)f2bf(wi1) << 16);
            }
        } else {
#pragma unroll
            for (int q = 0; q < 8; ++q) {
                *(unsigned*)&sWr[nW * WSTR + jh + 2 * q] = 0u;
                *(unsigned*)&sWi[nW * WSTR + jh + 2 * q] = 0u;
            }
        }
        __syncthreads();
#pragma unroll
        for (int ph = 0; ph < 2; ++ph) {
            const short* sA = ph ? sAi : sAr;
            const short* sW = ph ? sWi : sWr;
            short8 af[4], bf[4];
#pragma unroll
            for (int t = 0; t < 4; ++t) {
                af[t] = *(const short8*)&sA[(mw + t * 16 + rrow) * ASTR + quad * 8];
                bf[t] = *(const short8*)&sW[(nw + t * 16 + rrow) * WSTR + quad * 8];
            }
#pragma unroll
            for (int ti = 0; ti < 4; ++ti)
#pragma unroll
                for (int tj = 0; tj < 4; ++tj)
                    acc[ti][tj] = __builtin_amdgcn_mfma_f32_16x16x32_bf16(af[ti], bf[tj], acc[ti][tj], 0, 0, 0);
        }
        __syncthreads();
    }
#pragma unroll
    for (int ti = 0; ti < 4; ++ti) {
        int m = mw + ti * 16 + quad * 4;
#pragma unroll
        for (int tj = 0; tj < 4; ++tj) {
            int n = nw + tj * 16 + rrow;
            if (n < UU)
#pragma unroll
                for (int r = 0; r < 4; ++r)
                    atomicAdd(&dst[(size_t)(m + r) * UU + n], acc[ti][tj][r]);
        }
    }
}

extern "C" void kernel_launch(void* const* d_in, const int* in_sizes, int n_in,
                              void* d_out, int out_size, void* d_ws, size_t ws_size,
                              hipStream_t stream) {
    const float* Ar = (const float*)d_in[0];
    const float* Ai = (const float*)d_in[1];
    const float* Kt = (const float*)d_in[2];
    float* out = (float*)d_out;

    const size_t kb_need = (size_t)8 * 8 * 8 * 64 * 8 * sizeof(unsigned short); // 512 KB

    if (ws_size >= kb_need) {
        unsigned short* KbF = (unsigned short*)d_ws;
        hipLaunchKernelGGL(kbf_build_kernel, dim3(128), dim3(256), 0, stream, Kt, KbF, out);
        hipLaunchKernelGGL(qf_gemm_kernel, dim3(2048), dim3(512), 0, stream,
                           Ar, Ai, Kt, KbF, out);
    } else {
        hipLaunchKernelGGL(zero_out_kernel, dim3(100), dim3(256), 0, stream, out);
        hipLaunchKernelGGL(cm_gemm_fb_kernel, dim3(DD), dim3(512), 0, stream, Ar, Ai, Kt, out);
    }
}